// Round 3
// baseline (634.161 us; speedup 1.0000x reference)
//
#include <hip/hip_runtime.h>
#include <stdint.h>
#include <stddef.h>

#define NNODES 100000
#define NEDGES 3200000
#define INFEAT 512
#define HID 256
#define SMP 32768
#define BNEPS 1e-5f

// ---- degree histogram partition params ----
#define PA_EPB 4096                                   // edges per phase-A block
#define PA_BLOCKS ((NEDGES + PA_EPB - 1) / PA_EPB)    // 782
#define NBUCK 196                                     // bucket = node >> 9 (512 nodes/bucket)
#define BBITS 9

using half8 = __attribute__((ext_vector_type(8))) _Float16;
using f32x4 = __attribute__((ext_vector_type(4))) float;

__device__ __forceinline__ uint32_t rotl32(uint32_t x, int d) { return (x << d) | (x >> (32 - d)); }

// Threefry-2x32, 20 rounds, JAX key-injection schedule — bit-exact, DO NOT TOUCH (verified R1)
__device__ __forceinline__ void threefry2x32(uint32_t k0, uint32_t k1, uint32_t& x0, uint32_t& x1) {
  const uint32_t ks0 = k0, ks1 = k1, ks2 = k0 ^ k1 ^ 0x1BD11BDAu;
  x0 += ks0; x1 += ks1;
#define TFR(r) { x0 += x1; x1 = rotl32(x1, r); x1 ^= x0; }
  TFR(13) TFR(15) TFR(26) TFR(6)
  x0 += ks1; x1 += ks2 + 1u;
  TFR(17) TFR(29) TFR(16) TFR(24)
  x0 += ks2; x1 += ks0 + 2u;
  TFR(13) TFR(15) TFR(26) TFR(6)
  x0 += ks0; x1 += ks1 + 3u;
  TFR(17) TFR(29) TFR(16) TFR(24)
  x0 += ks1; x1 += ks2 + 4u;
  TFR(13) TFR(15) TFR(26) TFR(6)
  x0 += ks2; x1 += ks0 + 5u;
#undef TFR
}

// Phase A: block-local bucket sort of 4096 edges via LDS; zero global atomics.
// Also grid-stride clears mapping to -1 (folded memset; mapping first used by k_sample).
__global__ __launch_bounds__(256) void k_part(const int* __restrict__ erow,
                                              int* __restrict__ part, int* __restrict__ lbaseg,
                                              int* __restrict__ mapping) {
  __shared__ int hist[NBUCK];
  __shared__ int cnt2[NBUCK];
  __shared__ int base[NBUCK];
  __shared__ int sc[256];
  __shared__ int staged[PA_EPB];
  const int t = threadIdx.x;
  const int s = blockIdx.x;
  for (int i = s * 256 + t; i < NNODES; i += PA_BLOCKS * 256) mapping[i] = -1;
  const int e0 = s * PA_EPB;
  const int n = min(PA_EPB, NEDGES - e0);
  for (int i = t; i < NBUCK; i += 256) { hist[i] = 0; cnt2[i] = 0; }
  __syncthreads();
  int nodes[16];
  int cnt = 0;
  for (int i = t; i < n; i += 256) nodes[cnt++] = erow[e0 + i];   // coalesced
  for (int j = 0; j < cnt; ++j) atomicAdd(&hist[nodes[j] >> BBITS], 1);  // LDS atomic
  __syncthreads();
  sc[t] = (t < NBUCK) ? hist[t] : 0;
  __syncthreads();
  for (int o = 1; o < 256; o <<= 1) {
    int v = (t >= o) ? sc[t - o] : 0;
    __syncthreads();
    sc[t] += v;
    __syncthreads();
  }
  if (t < NBUCK) {
    base[t] = sc[t] - hist[t];                 // exclusive prefix
    lbaseg[s * NBUCK + t] = base[t];
  }
  __syncthreads();
  for (int j = 0; j < cnt; ++j) {
    int b = nodes[j] >> BBITS;
    int r = atomicAdd(&cnt2[b], 1);            // LDS atomic
    staged[base[b] + r] = nodes[j];
  }
  __syncthreads();
  for (int i = t; i < n; i += 256) part[e0 + i] = staged[i];      // coalesced
}

// Phase B: one block per bucket (512 nodes)
__global__ __launch_bounds__(256) void k_count(const int* __restrict__ part,
                                               const int* __restrict__ lbaseg, int* __restrict__ deg) {
  __shared__ int hist[512];
  const int t = threadIdx.x;
  const int b = blockIdx.x;
  for (int i = t; i < 512; i += 256) hist[i] = 0;
  __syncthreads();
  for (int s = t; s < PA_BLOCKS; s += 256) {
    const int e0 = s * PA_EPB;
    const int n = min(PA_EPB, NEDGES - e0);
    const int st = lbaseg[s * NBUCK + b];
    const int en = (b < NBUCK - 1) ? lbaseg[s * NBUCK + b + 1] : n;
    for (int i = st; i < en; ++i) {
      int node = part[e0 + i];
      atomicAdd(&hist[node & 511], 1);         // LDS atomic
    }
  }
  __syncthreads();
  const int n0 = b << BBITS;
  for (int i = t; i < 512; i += 256) {
    int idx = n0 + i;
    if (idx < NNODES) deg[idx] = hist[i];
  }
}

// ---- cumsum = bit-exact replica of XLA associative_scan tree, parallelized ----
__global__ __launch_bounds__(256) void k_down(const int* __restrict__ deg, float* __restrict__ E) {
  __shared__ float l0[4096];
  __shared__ float l1[2048];
  const int t = threadIdx.x;
  const int base0 = blockIdx.x * 4096;
  const int n0 = min(4096, NNODES - base0);
  for (int i = t; i < n0; i += 256) {
    float p = (float)deg[base0 + i] / 3200000.0f;  // deg.sum() exactly 3.2e6 in f32
    l0[i] = p;
    E[base0 + i] = p;
  }
  __syncthreads();
  const int b1 = base0 >> 1, n1 = min(2048, 50000 - b1);
  for (int k = t; k < n1; k += 256) { float v = l0[2*k] + l0[2*k+1]; l1[k] = v; E[100000 + b1 + k] = v; }
  __syncthreads();
  const int b2 = base0 >> 2, n2 = min(1024, 25000 - b2);
  for (int k = t; k < n2; k += 256) { float v = l1[2*k] + l1[2*k+1]; l0[k] = v; E[150000 + b2 + k] = v; }
  __syncthreads();
  const int b3 = base0 >> 3, n3 = min(512, 12500 - b3);
  for (int k = t; k < n3; k += 256) { float v = l0[2*k] + l0[2*k+1]; l1[k] = v; E[175000 + b3 + k] = v; }
  __syncthreads();
  const int b4 = base0 >> 4, n4 = min(256, 6250 - b4);
  for (int k = t; k < n4; k += 256) { float v = l1[2*k] + l1[2*k+1]; E[187500 + b4 + k] = v; }
}

__device__ __constant__ int kMidN[12] = {3125,1562,781,390,195,97,48,24,12,6,3,1};
__device__ __constant__ int kMidO[12] = {0,3125,4687,5468,5858,6053,6150,6198,6222,6234,6240,6243};
__global__ __launch_bounds__(1024) void k_mid(const float* __restrict__ E, float* __restrict__ CS) {
  __shared__ float eb[6244];
  __shared__ float sb[6244];
  const int t = threadIdx.x;
  const float* e4 = E + 187500;
  for (int k = t; k < 3125; k += 1024) eb[k] = e4[2*k] + e4[2*k+1];
  __syncthreads();
  for (int li = 1; li < 12; ++li) {
    const float* src = eb + kMidO[li-1];
    float* dst = eb + kMidO[li];
    const int n = kMidN[li];
    for (int k = t; k < n; k += 1024) dst[k] = src[2*k] + src[2*k+1];
    __syncthreads();
  }
  if (t == 0) sb[6243] = eb[6243];  // s16 = e16
  __syncthreads();
  for (int li = 10; li >= 0; --li) {
    const float* el = eb + kMidO[li];
    const float* sh = sb + kMidO[li+1];
    float* sl = sb + kMidO[li];
    const int n = kMidN[li], nh = kMidN[li+1];
    for (int k = t; k < nh; k += 1024) {
      float v = sh[k];
      sl[2*k+1] = v;
      if (2*k+2 < n) sl[2*k+2] = v + el[2*k+2];
    }
    if (t == 0) sl[0] = el[0];
    __syncthreads();
  }
  for (int k = t; k < 3125; k += 1024) CS[193750 + k] = sb[k];  // s5
}

// Fused up-sweep: s3125 -> 6250 -> 12500 -> 25000 -> 50000 -> CS[0..100000).
// Replaces 5 k_up launches. Each output = one add of the same operands as before
// (bit-exact); intermediate levels live only in LDS (nothing else reads them).
__global__ __launch_bounds__(256) void k_upall(const float* __restrict__ CStop,
                                               const float* __restrict__ E,
                                               float* __restrict__ CS) {
  __shared__ float s2[2050];  // n=50000 slice
  __shared__ float s3[1026];  // n=25000
  __shared__ float s4[514];   // n=12500
  __shared__ float s5[258];   // n=6250
  __shared__ float s6[132];   // n=3125 (top)
  const int t = threadIdx.x;
  const int lo1 = blockIdx.x * 4096;
  const int hi1 = min(100000, lo1 + 4096);
#define UPRANGE(lo, hi, plo, phi) { plo = (lo <= 1) ? 0 : ((lo - 1) >> 1); phi = (((hi) - 2) >> 1) + 1; }
  int lo2, hi2; UPRANGE(lo1, hi1, lo2, hi2)
  int lo3, hi3; UPRANGE(lo2, hi2, lo3, hi3)
  int lo4, hi4; UPRANGE(lo3, hi3, lo4, hi4)
  int lo5, hi5; UPRANGE(lo4, hi4, lo5, hi5)
  int lo6, hi6; UPRANGE(lo5, hi5, lo6, hi6)
#undef UPRANGE
  for (int k = lo6 + t; k < hi6; k += 256) s6[k - lo6] = CStop[k];
  __syncthreads();
#define EXPAND(dst, dlo, dhi, src, slo, el) \
  for (int j = dlo + t; j < dhi; j += 256) { \
    int p = (j <= 0) ? 0 : ((j - 1) >> 1); \
    float v = src[p - slo]; \
    dst[j - dlo] = (j == 0) ? (el)[0] : ((j & 1) ? v : v + (el)[j]); \
  } \
  __syncthreads();
  EXPAND(s5, lo5, hi5, s6, lo6, E + 187500)
  EXPAND(s4, lo4, hi4, s5, lo5, E + 175000)
  EXPAND(s3, lo3, hi3, s4, lo4, E + 150000)
  EXPAND(s2, lo2, hi2, s3, lo3, E + 100000)
#undef EXPAND
  for (int j = lo1 + t; j < hi1; j += 256) {
    int p = (j <= 0) ? 0 : ((j - 1) >> 1);
    float v = s2[p - lo2];
    CS[j] = (j == 0) ? E[0] : ((j & 1) ? v : v + E[j]);
  }
}

// partitionable-threefry choice + searchsorted left — bit-exact, verified R1.
// Also clears cnt (folded memset; cnt first used by k_edge_count).
__global__ __launch_bounds__(256) void k_sample(const float* __restrict__ cum, int* __restrict__ sampled,
                                                int* __restrict__ mapping, float* __restrict__ outSamp,
                                                int* __restrict__ cnt) {
  int i = blockIdx.x * 256 + threadIdx.x;
  if (i >= SMP) return;
  cnt[i] = 0;
  uint32_t x0 = 0u, x1 = (uint32_t)i;
  threefry2x32(0u, 42u, x0, x1);
  uint32_t bits = x0 ^ x1;
  float u = __uint_as_float((bits >> 9) | 0x3f800000u) - 1.0f;
  float r = cum[NNODES - 1] * (1.0f - u);
  int lo = 0, hi = NNODES;
  while (lo < hi) {
    int mid = (lo + hi) >> 1;
    if (cum[mid] < r) lo = mid + 1; else hi = mid;
  }
  if (lo > NNODES - 1) lo = NNODES - 1;
  sampled[i] = lo;
  outSamp[i] = (float)lo;
  atomicMax(&mapping[lo], i);
}

// ---- CSR build over valid edges keyed by destination position ----
__global__ __launch_bounds__(256) void k_edge_count(const int* __restrict__ erow, const int* __restrict__ ecol,
                                                    const int* __restrict__ mapping, int* __restrict__ cnt) {
  int i = blockIdx.x * 256 + threadIdx.x;
  if (i >= NEDGES) return;
  int r = mapping[erow[i]];
  int c = mapping[ecol[i]];
  if ((r | c) >= 0) atomicAdd(&cnt[c], 1);
}

__global__ __launch_bounds__(1024) void k_scan(const int* __restrict__ cnt, int* __restrict__ rowptr,
                                               int* __restrict__ cursor) {
  __shared__ int tot[1024];
  const int t = threadIdx.x;
  const int base = t * 32;
  int local[32];
  int s = 0;
#pragma unroll
  for (int i = 0; i < 32; ++i) { local[i] = s; s += cnt[base + i]; }
  tot[t] = s;
  __syncthreads();
  for (int o = 1; o < 1024; o <<= 1) {
    int v = (t >= o) ? tot[t - o] : 0;
    __syncthreads();
    tot[t] += v;
    __syncthreads();
  }
  int excl = (t == 0) ? 0 : tot[t - 1];
#pragma unroll
  for (int i = 0; i < 32; ++i) {
    int v = excl + local[i];
    rowptr[base + i] = v;
    cursor[base + i] = v;
  }
  if (t == 1023) rowptr[SMP] = tot[1023];
}

__global__ __launch_bounds__(256) void k_edge_fill(const int* __restrict__ erow, const int* __restrict__ ecol,
                                                   const int* __restrict__ mapping, int* __restrict__ cursor,
                                                   int* __restrict__ srcidx) {
  int i = blockIdx.x * 256 + threadIdx.x;
  if (i >= NEDGES) return;
  int r = mapping[erow[i]];
  int c = mapping[ecol[i]];
  if ((r | c) < 0) return;
  int pos = atomicAdd(&cursor[c], 1);
  srcidx[pos] = r;
}

// A[c,:] = sum over CSR bucket of S[r,:] — one wave per destination, no atomics.
// Block 0 also zeroes sums/sumsq (folded memset; consumed by the NEXT kernel, k_bn_stats).
__global__ __launch_bounds__(256) void k_segsum(const float* __restrict__ S, const int* __restrict__ rowptr,
                                                const int* __restrict__ srcidx, float* __restrict__ A,
                                                float* __restrict__ sums) {
  if (blockIdx.x == 0 && threadIdx.x < 512) sums[threadIdx.x] = 0.f;  // sums[256]+sumsq[256] contiguous
  const int wave = threadIdx.x >> 6, lane = threadIdx.x & 63;
  const int c = blockIdx.x * 4 + wave;
  const int b = rowptr[c], e = rowptr[c + 1];
  float4 acc = make_float4(0.f, 0.f, 0.f, 0.f);
  for (int i = b; i < e; ++i) {
    int r = srcidx[i];
    float4 v = *(const float4*)(S + (size_t)r * HID + lane * 4);
    acc.x += v.x; acc.y += v.y; acc.z += v.z; acc.w += v.w;
  }
  *(float4*)(A + (size_t)c * HID + lane * 4) = acc;
}

// out[c] = sum s3[r] + b3 — one thread per destination
__global__ __launch_bounds__(256) void k_segsum_sc(const float* __restrict__ s3, const int* __restrict__ rowptr,
                                                   const int* __restrict__ srcidx, const float* __restrict__ b3,
                                                   float* __restrict__ out) {
  int c = blockIdx.x * 256 + threadIdx.x;
  if (c >= SMP) return;
  float acc = 0.f;
  const int e = rowptr[c + 1];
  for (int i = rowptr[c]; i < e; ++i) acc += s3[srcidx[i]];
  out[c] = acc + b3[0];
}

// One-time weight split: W[K][256] fp32 -> Wh/Wl [256][K] f16 (transposed, fragment-friendly).
// hi = rne(x); lo = rne(x - hi): together 22 mantissa bits ≈ fp32.
// Single launch covers W1 (blocks 0..511) and W2 (blocks 512..767).
__global__ __launch_bounds__(256) void k_wsplit(const float* __restrict__ W1, _Float16* __restrict__ W1h,
                                                _Float16* __restrict__ W1l,
                                                const float* __restrict__ W2, _Float16* __restrict__ W2h,
                                                _Float16* __restrict__ W2l) {
  const float* W; _Float16 *Wh, *Wl; int K, i;
  if (blockIdx.x < INFEAT) {
    W = W1; Wh = W1h; Wl = W1l; K = INFEAT;
    i = blockIdx.x * 256 + threadIdx.x;
  } else {
    W = W2; Wh = W2h; Wl = W2l; K = HID;
    i = (blockIdx.x - INFEAT) * 256 + threadIdx.x;
  }
  int k = i & (K - 1);
  int c = i / K;
  float v = W[(size_t)k * HID + c];
  _Float16 h = (_Float16)v;
  Wh[(size_t)c * K + k] = h;
  Wl[(size_t)c * K + k] = (_Float16)(v - (float)h);
}

// C[M=32768, 256] = gather(A)@B via f16-split MFMA (Ootomo 3-term: AhBh + AhBl + AlBh).
// R2 post-mortem: LDS unit is CU-shared (~12cyc/b128 wave-inst) while MFMA pipes are
// per-SIMD; the old 24 LDS-insts : 48 MFMA ratio made the kernel ~3x LDS-issue-bound.
// Fix: B (<=512KB, L2-resident, shared by all blocks) fragments load DIRECTLY from
// global (per-lane 16B, 64B-granule coalesced L2 hits) — LDS now stages A only:
// 12 LDS insts : 48 MFMA -> predicted MfmaUtil ~2x.
// 128x128 block tile, 4 waves 2x2, 64x64/wave as 4x4 frags of 16x16x32.
__global__ __launch_bounds__(256) void k_gemm_h(const float* __restrict__ Am,
                                                const _Float16* __restrict__ Bth,
                                                const _Float16* __restrict__ Btl,
                                                float* __restrict__ Cm,
                                                const int* __restrict__ gather, int K) {
  __shared__ alignas(16) _Float16 Ahs[128][40];  // [row][k], pad 40 keeps 16B align + 2-way banks
  __shared__ alignas(16) _Float16 Als[128][40];
  const int t = threadIdx.x;
  const int lane = t & 63, wave = t >> 6;
  const int wm = wave >> 1, wn = wave & 1;
  const int l15 = lane & 15, g = lane >> 4;
  const int row0 = blockIdx.x * 128, col0 = blockIdx.y * 128;

  // A staging: thread -> (row sr, k-half sk)
  const int sr = t >> 1;
  const int sk = (t & 1) << 4;
  int arow = row0 + sr;
  if (gather) arow = gather[arow];
  const float* aptr = Am + (size_t)arow * K + sk;
  // B fragment bases for this wave (direct global; col = col0 + wn*64 + nf*16 + l15)
  const _Float16* bbh = Bth + (size_t)(col0 + wn * 64 + l15) * K + g * 8;
  const _Float16* bbl = Btl + (size_t)(col0 + wn * 64 + l15) * K + g * 8;

  f32x4 acc[4][4] = {};

  float4 pa0, pa1, pa2, pa3;
#define LOADSLAB(kk) { \
    pa0 = *(const float4*)(aptr + (kk));      pa1 = *(const float4*)(aptr + (kk) + 4); \
    pa2 = *(const float4*)(aptr + (kk) + 8);  pa3 = *(const float4*)(aptr + (kk) + 12); }

  LOADSLAB(0);
  for (int k0 = 0; k0 < K; k0 += 32) {
    // fp32 -> f16 hi/lo split (VALU, overlaps barrier wait)
    half8 h0, h1, l0, l1;
#define SPLIT4(v, H, L, b) { \
    H[b+0] = (_Float16)v.x; L[b+0] = (_Float16)(v.x - (float)H[b+0]); \
    H[b+1] = (_Float16)v.y; L[b+1] = (_Float16)(v.y - (float)H[b+1]); \
    H[b+2] = (_Float16)v.z; L[b+2] = (_Float16)(v.z - (float)H[b+2]); \
    H[b+3] = (_Float16)v.w; L[b+3] = (_Float16)(v.w - (float)H[b+3]); }
    SPLIT4(pa0, h0, l0, 0) SPLIT4(pa1, h0, l0, 4)
    SPLIT4(pa2, h1, l1, 0) SPLIT4(pa3, h1, l1, 4)
#undef SPLIT4
    __syncthreads();   // previous slab's A-frag reads done before overwrite
    *(half8*)&Ahs[sr][sk] = h0;  *(half8*)&Ahs[sr][sk + 8] = h1;
    *(half8*)&Als[sr][sk] = l0;  *(half8*)&Als[sr][sk + 8] = l1;
    __syncthreads();
    if (k0 + 32 < K) LOADSLAB(k0 + 32);  // A prefetch overlaps MFMA below

    // B fragments direct from global (L2-hit), issued before the ds_reads
    half8 fbh[4], fbl[4];
#pragma unroll
    for (int nf = 0; nf < 4; ++nf) {
      fbh[nf] = *(const half8*)(bbh + (size_t)nf * 16 * K + k0);
      fbl[nf] = *(const half8*)(bbl + (size_t)nf * 16 * K + k0);
    }
    half8 fah[4], fal[4];
#pragma unroll
    for (int mf = 0; mf < 4; ++mf) {
      const int r = wm * 64 + mf * 16 + l15;
      fah[mf] = *(const half8*)&Ahs[r][g * 8];
      fal[mf] = *(const half8*)&Als[r][g * 8];
    }
#pragma unroll
    for (int nf = 0; nf < 4; ++nf) {
#pragma unroll
      for (int mf = 0; mf < 4; ++mf) {
        acc[mf][nf] = __builtin_amdgcn_mfma_f32_16x16x32_f16(fah[mf], fbh[nf], acc[mf][nf], 0, 0, 0);
        acc[mf][nf] = __builtin_amdgcn_mfma_f32_16x16x32_f16(fah[mf], fbl[nf], acc[mf][nf], 0, 0, 0);
        acc[mf][nf] = __builtin_amdgcn_mfma_f32_16x16x32_f16(fal[mf], fbh[nf], acc[mf][nf], 0, 0, 0);
      }
    }
  }
#undef LOADSLAB
#pragma unroll
  for (int mf = 0; mf < 4; ++mf) {
#pragma unroll
    for (int nf = 0; nf < 4; ++nf) {
      const int r = row0 + wm * 64 + mf * 16 + g * 4;
      float* cp = Cm + (size_t)r * HID + col0 + wn * 64 + nf * 16 + l15;
#pragma unroll
      for (int reg = 0; reg < 4; ++reg) cp[(size_t)reg * HID] = acc[mf][nf][reg];
    }
  }
}

__global__ __launch_bounds__(256) void k_bn_stats(const float* __restrict__ A, const float* __restrict__ bias,
                                                  float* __restrict__ sums, float* __restrict__ sumsq) {
  const int c = threadIdx.x;
  const float b = bias[c];
  float s = 0.f, q = 0.f;
  const int r0 = blockIdx.x * (SMP / 256);
  for (int r = r0; r < r0 + (SMP / 256); ++r) {
    float h = A[(size_t)r * HID + c] + b;
    s += h;
    q = fmaf(h, h, q);
  }
  unsafeAtomicAdd(&sums[c], s);
  unsafeAtomicAdd(&sumsq[c], q);
}

// BN final folded in: per-thread channel quad is grid-stride-invariant, so
// scale/shift are computed once and hoisted (same fp32 ops as k_bn_final -> bit-exact).
__global__ __launch_bounds__(256) void k_bn_apply(const float* __restrict__ A, const float* __restrict__ bias,
    const float* __restrict__ sums, const float* __restrict__ sumsq,
    const float* __restrict__ gamma, const float* __restrict__ beta, float* __restrict__ Hh) {
  const int total = SMP * HID / 4;
  const int i0 = blockIdx.x * 256 + threadIdx.x;
  const int c = (i0 & (HID / 4 - 1)) * 4;
  float sc[4], sh[4], bs[4];
#pragma unroll
  for (int j = 0; j < 4; ++j) {
    float mu = sums[c + j] * (1.0f / SMP);
    float var = fmaxf(sumsq[c + j] * (1.0f / SMP) - mu * mu, 0.0f);
    float s = gamma[c + j] / sqrtf(var + BNEPS);
    sc[j] = s;
    sh[j] = beta[c + j] - mu * s;
    bs[j] = bias[c + j];
  }
  for (int i = i0; i < total; i += gridDim.x * 256) {
    float4 v = ((const float4*)A)[i];
    v.x = fmaxf(fmaf(v.x + bs[0], sc[0], sh[0]), 0.f);
    v.y = fmaxf(fmaf(v.y + bs[1], sc[1], sh[1]), 0.f);
    v.z = fmaxf(fmaf(v.z + bs[2], sc[2], sh[2]), 0.f);
    v.w = fmaxf(fmaf(v.w + bs[3], sc[3], sh[3]), 0.f);
    ((float4*)Hh)[i] = v;
  }
}

// s3[i] = dot(H[i,:], W3[:,0]); one wave per row
__global__ __launch_bounds__(256) void k_gemv3(const float* __restrict__ Hh, const float* __restrict__ W3,
                                               float* __restrict__ s3) {
  const int wave = threadIdx.x >> 6, lane = threadIdx.x & 63;
  const int row = blockIdx.x * 4 + wave;
  float4 h = *(const float4*)(Hh + (size_t)row * HID + lane * 4);
  float4 w = *(const float4*)(W3 + lane * 4);
  float d = h.x * w.x + h.y * w.y + h.z * w.z + h.w * w.w;
#pragma unroll
  for (int o = 32; o > 0; o >>= 1) d += __shfl_down(d, o);
  if (lane == 0) s3[row] = d;
}

extern "C" void kernel_launch(void* const* d_in, const int* in_sizes, int n_in,
                              void* d_out, int out_size, void* d_ws, size_t ws_size,
                              hipStream_t stream) {
  (void)in_sizes; (void)n_in; (void)out_size; (void)ws_size;
  const float* x   = (const float*)d_in[0];
  const int*  eidx = (const int*)d_in[1];
  const float* W1  = (const float*)d_in[2];
  const float* b1  = (const float*)d_in[3];
  const float* W2  = (const float*)d_in[4];
  const float* b2  = (const float*)d_in[5];
  const float* W3  = (const float*)d_in[6];
  const float* b3  = (const float*)d_in[7];
  const float* g1  = (const float*)d_in[8];
  const float* be1 = (const float*)d_in[9];
  const float* g2  = (const float*)d_in[10];
  const float* be2 = (const float*)d_in[11];
  const int* erow = eidx;
  const int* ecol = eidx + NEDGES;

  float* out = (float*)d_out;        // [32768] conv3 output
  float* outSamp = out + SMP;        // [32768] sampled indices as f32

  size_t off = 0;
  auto take = [&](size_t bytes) -> char* {
    char* p = (char*)d_ws + off;
    off += (bytes + 255) & ~(size_t)255;
    return p;
  };
  float* S       = (float*)take((size_t)SMP * HID * 4);  // support / s3
  float* A       = (float*)take((size_t)SMP * HID * 4);  // segsum output
  float* H       = (float*)take((size_t)SMP * HID * 4);  // post-BN activations
  float* E       = (float*)take(199994 * 4);             // down-sweep levels
  float* CS      = (float*)take(199994 * 4);             // up-sweep levels (CS[0..100000) = result)
  int*   deg     = (int*)take(NNODES * 4);
  int*   part    = (int*)take((size_t)NEDGES * 4);       // bucket-partitioned edge rows
  int*   lbaseg  = (int*)take((size_t)PA_BLOCKS * NBUCK * 4);  // per-block bucket bases
  int*   mapping = (int*)take(NNODES * 4);
  int*   sampled = (int*)take(SMP * 4);
  float* sums    = (float*)take(HID * 4 * 2);
  float* sumsq   = sums + HID;
  float* scale   = (float*)take(HID * 4);   // (unused, kept for ws layout stability)
  float* shift   = (float*)take(HID * 4);
  int*   cnt     = (int*)take(SMP * 4);
  int*   rowptr  = (int*)take((SMP + 1) * 4);
  int*   cursor  = (int*)take(SMP * 4);
  int*   srcidx  = (int*)take((size_t)NEDGES * 4);
  _Float16* W1h  = (_Float16*)take((size_t)INFEAT * HID * 2);  // [256][512]
  _Float16* W1l  = (_Float16*)take((size_t)INFEAT * HID * 2);
  _Float16* W2h  = (_Float16*)take((size_t)HID * HID * 2);     // [256][256]
  _Float16* W2l  = (_Float16*)take((size_t)HID * HID * 2);
  (void)scale; (void)shift;
  // total ws need ~= 131 MB

  // one-time weight splits (f16 hi/lo, transposed); single launch
  k_wsplit<<<INFEAT + HID, 256, 0, stream>>>(W1, W1h, W1l, W2, W2h, W2l);

  // degree histogram, atomic-free (two-phase partition); k_part also clears mapping
  k_part<<<PA_BLOCKS, 256, 0, stream>>>(erow, part, lbaseg, mapping);
  k_count<<<NBUCK, 256, 0, stream>>>(part, lbaseg, deg);

  // cumsum: parallel bit-exact tree (down-sweep, mid, fused up-sweep)
  k_down<<<25, 256, 0, stream>>>(deg, E);
  k_mid<<<1, 1024, 0, stream>>>(E, CS);
  k_upall<<<25, 256, 0, stream>>>(CS + 193750, E, CS);

  k_sample<<<SMP / 256, 256, 0, stream>>>(CS, sampled, mapping, outSamp, cnt);

  // CSR over valid edges, keyed by destination position
  k_edge_count<<<(NEDGES + 255) / 256, 256, 0, stream>>>(erow, ecol, mapping, cnt);
  k_scan<<<1, 1024, 0, stream>>>(cnt, rowptr, cursor);
  k_edge_fill<<<(NEDGES + 255) / 256, 256, 0, stream>>>(erow, ecol, mapping, cursor, srcidx);

  // layer 1: conv(x@W1) -> BN -> relu
  k_gemm_h<<<dim3(SMP / 128, HID / 128), 256, 0, stream>>>(x, W1h, W1l, S, sampled, INFEAT);
  k_segsum<<<SMP / 4, 256, 0, stream>>>(S, rowptr, srcidx, A, sums);
  k_bn_stats<<<256, 256, 0, stream>>>(A, b1, sums, sumsq);
  k_bn_apply<<<2048, 256, 0, stream>>>(A, b1, sums, sumsq, g1, be1, H);

  // layer 2
  k_gemm_h<<<dim3(SMP / 128, HID / 128), 256, 0, stream>>>(H, W2h, W2l, S, nullptr, HID);
  k_segsum<<<SMP / 4, 256, 0, stream>>>(S, rowptr, srcidx, A, sums);
  k_bn_stats<<<256, 256, 0, stream>>>(A, b2, sums, sumsq);
  k_bn_apply<<<2048, 256, 0, stream>>>(A, b2, sums, sumsq, g2, be2, H);

  // layer 3: gemv + CSR segsum + bias
  k_gemv3<<<SMP / 4, 256, 0, stream>>>(H, W3, S);  // S reused as s3
  k_segsum_sc<<<SMP / 256, 256, 0, stream>>>(S, rowptr, srcidx, b3, out);
}

// Round 4
// 597.286 us; speedup vs baseline: 1.0617x; 1.0617x over previous
//
#include <hip/hip_runtime.h>
#include <stdint.h>
#include <stddef.h>

#define NNODES 100000
#define NEDGES 3200000
#define INFEAT 512
#define HID 256
#define SMP 32768
#define BNEPS 1e-5f

// ---- degree histogram partition params ----
#define PA_EPB 4096                                   // edges per phase-A block
#define PA_BLOCKS ((NEDGES + PA_EPB - 1) / PA_EPB)    // 782
#define NBUCK 196                                     // bucket = node >> 9 (512 nodes/bucket)
#define BBITS 9

using half8 = __attribute__((ext_vector_type(8))) _Float16;
using f32x4 = __attribute__((ext_vector_type(4))) float;

__device__ __forceinline__ uint32_t rotl32(uint32_t x, int d) { return (x << d) | (x >> (32 - d)); }

// Threefry-2x32, 20 rounds, JAX key-injection schedule — bit-exact, DO NOT TOUCH (verified R1)
__device__ __forceinline__ void threefry2x32(uint32_t k0, uint32_t k1, uint32_t& x0, uint32_t& x1) {
  const uint32_t ks0 = k0, ks1 = k1, ks2 = k0 ^ k1 ^ 0x1BD11BDAu;
  x0 += ks0; x1 += ks1;
#define TFR(r) { x0 += x1; x1 = rotl32(x1, r); x1 ^= x0; }
  TFR(13) TFR(15) TFR(26) TFR(6)
  x0 += ks1; x1 += ks2 + 1u;
  TFR(17) TFR(29) TFR(16) TFR(24)
  x0 += ks2; x1 += ks0 + 2u;
  TFR(13) TFR(15) TFR(26) TFR(6)
  x0 += ks0; x1 += ks1 + 3u;
  TFR(17) TFR(29) TFR(16) TFR(24)
  x0 += ks1; x1 += ks2 + 4u;
  TFR(13) TFR(15) TFR(26) TFR(6)
  x0 += ks2; x1 += ks0 + 5u;
#undef TFR
}

// Phase A: block-local bucket sort of 4096 edges via LDS; zero global atomics.
// Also grid-stride clears mapping to -1 (folded memset; mapping first used by k_sample).
__global__ __launch_bounds__(256) void k_part(const int* __restrict__ erow,
                                              int* __restrict__ part, int* __restrict__ lbaseg,
                                              int* __restrict__ mapping) {
  __shared__ int hist[NBUCK];
  __shared__ int cnt2[NBUCK];
  __shared__ int base[NBUCK];
  __shared__ int sc[256];
  __shared__ int staged[PA_EPB];
  const int t = threadIdx.x;
  const int s = blockIdx.x;
  for (int i = s * 256 + t; i < NNODES; i += PA_BLOCKS * 256) mapping[i] = -1;
  const int e0 = s * PA_EPB;
  const int n = min(PA_EPB, NEDGES - e0);
  for (int i = t; i < NBUCK; i += 256) { hist[i] = 0; cnt2[i] = 0; }
  __syncthreads();
  int nodes[16];
  int cnt = 0;
  for (int i = t; i < n; i += 256) nodes[cnt++] = erow[e0 + i];   // coalesced
  for (int j = 0; j < cnt; ++j) atomicAdd(&hist[nodes[j] >> BBITS], 1);  // LDS atomic
  __syncthreads();
  sc[t] = (t < NBUCK) ? hist[t] : 0;
  __syncthreads();
  for (int o = 1; o < 256; o <<= 1) {
    int v = (t >= o) ? sc[t - o] : 0;
    __syncthreads();
    sc[t] += v;
    __syncthreads();
  }
  if (t < NBUCK) {
    base[t] = sc[t] - hist[t];                 // exclusive prefix
    lbaseg[s * NBUCK + t] = base[t];
  }
  __syncthreads();
  for (int j = 0; j < cnt; ++j) {
    int b = nodes[j] >> BBITS;
    int r = atomicAdd(&cnt2[b], 1);            // LDS atomic
    staged[base[b] + r] = nodes[j];
  }
  __syncthreads();
  for (int i = t; i < n; i += 256) part[e0 + i] = staged[i];      // coalesced
}

// Phase B: one block per bucket (512 nodes)
__global__ __launch_bounds__(256) void k_count(const int* __restrict__ part,
                                               const int* __restrict__ lbaseg, int* __restrict__ deg) {
  __shared__ int hist[512];
  const int t = threadIdx.x;
  const int b = blockIdx.x;
  for (int i = t; i < 512; i += 256) hist[i] = 0;
  __syncthreads();
  for (int s = t; s < PA_BLOCKS; s += 256) {
    const int e0 = s * PA_EPB;
    const int n = min(PA_EPB, NEDGES - e0);
    const int st = lbaseg[s * NBUCK + b];
    const int en = (b < NBUCK - 1) ? lbaseg[s * NBUCK + b + 1] : n;
    for (int i = st; i < en; ++i) {
      int node = part[e0 + i];
      atomicAdd(&hist[node & 511], 1);         // LDS atomic
    }
  }
  __syncthreads();
  const int n0 = b << BBITS;
  for (int i = t; i < 512; i += 256) {
    int idx = n0 + i;
    if (idx < NNODES) deg[idx] = hist[i];
  }
}

// ---- cumsum = bit-exact replica of XLA associative_scan tree, parallelized ----
__global__ __launch_bounds__(256) void k_down(const int* __restrict__ deg, float* __restrict__ E) {
  __shared__ float l0[4096];
  __shared__ float l1[2048];
  const int t = threadIdx.x;
  const int base0 = blockIdx.x * 4096;
  const int n0 = min(4096, NNODES - base0);
  for (int i = t; i < n0; i += 256) {
    float p = (float)deg[base0 + i] / 3200000.0f;  // deg.sum() exactly 3.2e6 in f32
    l0[i] = p;
    E[base0 + i] = p;
  }
  __syncthreads();
  const int b1 = base0 >> 1, n1 = min(2048, 50000 - b1);
  for (int k = t; k < n1; k += 256) { float v = l0[2*k] + l0[2*k+1]; l1[k] = v; E[100000 + b1 + k] = v; }
  __syncthreads();
  const int b2 = base0 >> 2, n2 = min(1024, 25000 - b2);
  for (int k = t; k < n2; k += 256) { float v = l1[2*k] + l1[2*k+1]; l0[k] = v; E[150000 + b2 + k] = v; }
  __syncthreads();
  const int b3 = base0 >> 3, n3 = min(512, 12500 - b3);
  for (int k = t; k < n3; k += 256) { float v = l0[2*k] + l0[2*k+1]; l1[k] = v; E[175000 + b3 + k] = v; }
  __syncthreads();
  const int b4 = base0 >> 4, n4 = min(256, 6250 - b4);
  for (int k = t; k < n4; k += 256) { float v = l1[2*k] + l1[2*k+1]; E[187500 + b4 + k] = v; }
}

__device__ __constant__ int kMidN[12] = {3125,1562,781,390,195,97,48,24,12,6,3,1};
__device__ __constant__ int kMidO[12] = {0,3125,4687,5468,5858,6053,6150,6198,6222,6234,6240,6243};
__global__ __launch_bounds__(1024) void k_mid(const float* __restrict__ E, float* __restrict__ CS) {
  __shared__ float eb[6244];
  __shared__ float sb[6244];
  const int t = threadIdx.x;
  const float* e4 = E + 187500;
  for (int k = t; k < 3125; k += 1024) eb[k] = e4[2*k] + e4[2*k+1];
  __syncthreads();
  for (int li = 1; li < 12; ++li) {
    const float* src = eb + kMidO[li-1];
    float* dst = eb + kMidO[li];
    const int n = kMidN[li];
    for (int k = t; k < n; k += 1024) dst[k] = src[2*k] + src[2*k+1];
    __syncthreads();
  }
  if (t == 0) sb[6243] = eb[6243];  // s16 = e16
  __syncthreads();
  for (int li = 10; li >= 0; --li) {
    const float* el = eb + kMidO[li];
    const float* sh = sb + kMidO[li+1];
    float* sl = sb + kMidO[li];
    const int n = kMidN[li], nh = kMidN[li+1];
    for (int k = t; k < nh; k += 1024) {
      float v = sh[k];
      sl[2*k+1] = v;
      if (2*k+2 < n) sl[2*k+2] = v + el[2*k+2];
    }
    if (t == 0) sl[0] = el[0];
    __syncthreads();
  }
  for (int k = t; k < 3125; k += 1024) CS[193750 + k] = sb[k];  // s5
}

// Fused up-sweep: s3125 -> 6250 -> 12500 -> 25000 -> 50000 -> CS[0..100000).
// Replaces 5 k_up launches; each output = one add of the same operands (bit-exact).
__global__ __launch_bounds__(256) void k_upall(const float* __restrict__ CStop,
                                               const float* __restrict__ E,
                                               float* __restrict__ CS) {
  __shared__ float s2[2050];  // n=50000 slice
  __shared__ float s3[1026];  // n=25000
  __shared__ float s4[514];   // n=12500
  __shared__ float s5[258];   // n=6250
  __shared__ float s6[132];   // n=3125 (top)
  const int t = threadIdx.x;
  const int lo1 = blockIdx.x * 4096;
  const int hi1 = min(100000, lo1 + 4096);
#define UPRANGE(lo, hi, plo, phi) { plo = (lo <= 1) ? 0 : ((lo - 1) >> 1); phi = (((hi) - 2) >> 1) + 1; }
  int lo2, hi2; UPRANGE(lo1, hi1, lo2, hi2)
  int lo3, hi3; UPRANGE(lo2, hi2, lo3, hi3)
  int lo4, hi4; UPRANGE(lo3, hi3, lo4, hi4)
  int lo5, hi5; UPRANGE(lo4, hi4, lo5, hi5)
  int lo6, hi6; UPRANGE(lo5, hi5, lo6, hi6)
#undef UPRANGE
  for (int k = lo6 + t; k < hi6; k += 256) s6[k - lo6] = CStop[k];
  __syncthreads();
#define EXPAND(dst, dlo, dhi, src, slo, el) \
  for (int j = dlo + t; j < dhi; j += 256) { \
    int p = (j <= 0) ? 0 : ((j - 1) >> 1); \
    float v = src[p - slo]; \
    dst[j - dlo] = (j == 0) ? (el)[0] : ((j & 1) ? v : v + (el)[j]); \
  } \
  __syncthreads();
  EXPAND(s5, lo5, hi5, s6, lo6, E + 187500)
  EXPAND(s4, lo4, hi4, s5, lo5, E + 175000)
  EXPAND(s3, lo3, hi3, s4, lo4, E + 150000)
  EXPAND(s2, lo2, hi2, s3, lo3, E + 100000)
#undef EXPAND
  for (int j = lo1 + t; j < hi1; j += 256) {
    int p = (j <= 0) ? 0 : ((j - 1) >> 1);
    float v = s2[p - lo2];
    CS[j] = (j == 0) ? E[0] : ((j & 1) ? v : v + E[j]);
  }
}

// partitionable-threefry choice + searchsorted left — bit-exact, verified R1.
// Also clears cnt (folded memset; cnt first used by k_edge_count).
__global__ __launch_bounds__(256) void k_sample(const float* __restrict__ cum, int* __restrict__ sampled,
                                                int* __restrict__ mapping, float* __restrict__ outSamp,
                                                int* __restrict__ cnt) {
  int i = blockIdx.x * 256 + threadIdx.x;
  if (i >= SMP) return;
  cnt[i] = 0;
  uint32_t x0 = 0u, x1 = (uint32_t)i;
  threefry2x32(0u, 42u, x0, x1);
  uint32_t bits = x0 ^ x1;
  float u = __uint_as_float((bits >> 9) | 0x3f800000u) - 1.0f;
  float r = cum[NNODES - 1] * (1.0f - u);
  int lo = 0, hi = NNODES;
  while (lo < hi) {
    int mid = (lo + hi) >> 1;
    if (cum[mid] < r) lo = mid + 1; else hi = mid;
  }
  if (lo > NNODES - 1) lo = NNODES - 1;
  sampled[i] = lo;
  outSamp[i] = (float)lo;
  atomicMax(&mapping[lo], i);
}

// ---- CSR build over valid edges keyed by destination position ----
__global__ __launch_bounds__(256) void k_edge_count(const int* __restrict__ erow, const int* __restrict__ ecol,
                                                    const int* __restrict__ mapping, int* __restrict__ cnt) {
  int i = blockIdx.x * 256 + threadIdx.x;
  if (i >= NEDGES) return;
  int r = mapping[erow[i]];
  int c = mapping[ecol[i]];
  if ((r | c) >= 0) atomicAdd(&cnt[c], 1);
}

__global__ __launch_bounds__(1024) void k_scan(const int* __restrict__ cnt, int* __restrict__ rowptr,
                                               int* __restrict__ cursor) {
  __shared__ int tot[1024];
  const int t = threadIdx.x;
  const int base = t * 32;
  int local[32];
  int s = 0;
#pragma unroll
  for (int i = 0; i < 32; ++i) { local[i] = s; s += cnt[base + i]; }
  tot[t] = s;
  __syncthreads();
  for (int o = 1; o < 1024; o <<= 1) {
    int v = (t >= o) ? tot[t - o] : 0;
    __syncthreads();
    tot[t] += v;
    __syncthreads();
  }
  int excl = (t == 0) ? 0 : tot[t - 1];
#pragma unroll
  for (int i = 0; i < 32; ++i) {
    int v = excl + local[i];
    rowptr[base + i] = v;
    cursor[base + i] = v;
  }
  if (t == 1023) rowptr[SMP] = tot[1023];
}

__global__ __launch_bounds__(256) void k_edge_fill(const int* __restrict__ erow, const int* __restrict__ ecol,
                                                   const int* __restrict__ mapping, int* __restrict__ cursor,
                                                   int* __restrict__ srcidx) {
  int i = blockIdx.x * 256 + threadIdx.x;
  if (i >= NEDGES) return;
  int r = mapping[erow[i]];
  int c = mapping[ecol[i]];
  if ((r | c) < 0) return;
  int pos = atomicAdd(&cursor[c], 1);
  srcidx[pos] = r;
}

// A[c,:] = sum over CSR bucket of S[r,:] — one wave per destination, no atomics.
// Block 0 also zeroes sums/sumsq (folded memset; consumed by the NEXT kernel, k_bn_stats).
__global__ __launch_bounds__(256) void k_segsum(const float* __restrict__ S, const int* __restrict__ rowptr,
                                                const int* __restrict__ srcidx, float* __restrict__ A,
                                                float* __restrict__ sums) {
  if (blockIdx.x == 0 && threadIdx.x < 512) sums[threadIdx.x] = 0.f;  // sums[256]+sumsq[256] contiguous
  const int wave = threadIdx.x >> 6, lane = threadIdx.x & 63;
  const int c = blockIdx.x * 4 + wave;
  const int b = rowptr[c], e = rowptr[c + 1];
  float4 acc = make_float4(0.f, 0.f, 0.f, 0.f);
  for (int i = b; i < e; ++i) {
    int r = srcidx[i];
    float4 v = *(const float4*)(S + (size_t)r * HID + lane * 4);
    acc.x += v.x; acc.y += v.y; acc.z += v.z; acc.w += v.w;
  }
  *(float4*)(A + (size_t)c * HID + lane * 4) = acc;
}

// out[c] = sum s3[r] + b3 — one thread per destination
__global__ __launch_bounds__(256) void k_segsum_sc(const float* __restrict__ s3, const int* __restrict__ rowptr,
                                                   const int* __restrict__ srcidx, const float* __restrict__ b3,
                                                   float* __restrict__ out) {
  int c = blockIdx.x * 256 + threadIdx.x;
  if (c >= SMP) return;
  float acc = 0.f;
  const int e = rowptr[c + 1];
  for (int i = rowptr[c]; i < e; ++i) acc += s3[srcidx[i]];
  out[c] = acc + b3[0];
}

// One-time weight split: W[K][256] fp32 -> Wh/Wl [256][K] f16 (transposed, fragment-friendly).
// Single launch covers W1 (blocks 0..511) and W2 (blocks 512..767).
__global__ __launch_bounds__(256) void k_wsplit(const float* __restrict__ W1, _Float16* __restrict__ W1h,
                                                _Float16* __restrict__ W1l,
                                                const float* __restrict__ W2, _Float16* __restrict__ W2h,
                                                _Float16* __restrict__ W2l) {
  const float* W; _Float16 *Wh, *Wl; int K, i;
  if (blockIdx.x < INFEAT) {
    W = W1; Wh = W1h; Wl = W1l; K = INFEAT;
    i = blockIdx.x * 256 + threadIdx.x;
  } else {
    W = W2; Wh = W2h; Wl = W2l; K = HID;
    i = (blockIdx.x - INFEAT) * 256 + threadIdx.x;
  }
  int k = i & (K - 1);
  int c = i / K;
  float v = W[(size_t)k * HID + c];
  _Float16 h = (_Float16)v;
  Wh[(size_t)c * K + k] = h;
  Wl[(size_t)c * K + k] = (_Float16)(v - (float)h);
}

// BN finalize: scale/shift per channel (tiny 1-block kernel; original R0 expressions).
__global__ __launch_bounds__(256) void k_bn_final(const float* __restrict__ sums, const float* __restrict__ sumsq,
    const float* __restrict__ gamma, const float* __restrict__ beta,
    float* __restrict__ scale, float* __restrict__ shift) {
  int c = threadIdx.x;
  float mu = sums[c] * (1.0f / SMP);
  float var = fmaxf(sumsq[c] * (1.0f / SMP) - mu * mu, 0.0f);
  float sc = gamma[c] / sqrtf(var + BNEPS);
  scale[c] = sc;
  shift[c] = beta[c] - mu * sc;
}

// C[M=32768, 256] = gather(A)@B via f16-split MFMA (Ootomo 3-term: AhBh + AhBl + AlBh).
// R3: reverted to full-LDS staging for A AND B (R2's B-direct-from-global was a
// 1KB-strided 64-lane gather — L2 transaction amplification cost ~+25µs; proven-620
// structure restored). NEW: optional fused BN+ReLU applied to A elements at staging
// (scale!=nullptr path) — exact same fmaf/fmax sequence as the old k_bn_apply, so
// bit-identical while eliminating the 64MB bn_apply pass per layer.
// 128x128 block tile, 4 waves 2x2, 64x64/wave as 4x4 frags of 16x16x32.
__global__ __launch_bounds__(256) void k_gemm_h(const float* __restrict__ Am,
                                                const _Float16* __restrict__ Bth,
                                                const _Float16* __restrict__ Btl,
                                                float* __restrict__ Cm,
                                                const int* __restrict__ gather, int K,
                                                const float* __restrict__ scale,
                                                const float* __restrict__ shift,
                                                const float* __restrict__ bias) {
  __shared__ alignas(16) _Float16 Ahs[128][40];  // [row][k], pad 40 keeps 16B align + 2-way banks
  __shared__ alignas(16) _Float16 Als[128][40];
  __shared__ alignas(16) _Float16 Bhs[128][40];  // [col][k]
  __shared__ alignas(16) _Float16 Bls[128][40];
  const int t = threadIdx.x;
  const int lane = t & 63, wave = t >> 6;
  const int wm = wave >> 1, wn = wave & 1;
  const int l15 = lane & 15, g = lane >> 4;
  const int row0 = blockIdx.x * 128, col0 = blockIdx.y * 128;

  // staging: thread -> (row/col sr, k-half sk)
  const int sr = t >> 1;
  const int sk = (t & 1) << 4;
  int arow = row0 + sr;
  if (gather) arow = gather[arow];
  const float* aptr = Am + (size_t)arow * K + sk;
  const _Float16* bhp = Bth + (size_t)(col0 + sr) * K + sk;
  const _Float16* blp = Btl + (size_t)(col0 + sr) * K + sk;

  f32x4 acc[4][4] = {};

  float4 pa0, pa1, pa2, pa3;
  uint4 pbh0, pbh1, pbl0, pbl1;
#define LOADSLAB(kk) { \
    pa0 = *(const float4*)(aptr + (kk));      pa1 = *(const float4*)(aptr + (kk) + 4); \
    pa2 = *(const float4*)(aptr + (kk) + 8);  pa3 = *(const float4*)(aptr + (kk) + 12); \
    pbh0 = *(const uint4*)(bhp + (kk)); pbh1 = *(const uint4*)(bhp + (kk) + 8); \
    pbl0 = *(const uint4*)(blp + (kk)); pbl1 = *(const uint4*)(blp + (kk) + 8); }

  LOADSLAB(0);
  for (int k0 = 0; k0 < K; k0 += 32) {
    // fused BN+ReLU on A (layer-2 path): h = relu(fmaf(v+bias, scale, shift)) — bit-
    // identical to the old k_bn_apply elementwise pass. scale/shift/bias are 1-3KB,
    // L1-resident after slab 0.
    if (scale) {
      const int ch = k0 + sk;
      const float4 sc0 = *(const float4*)(scale + ch),  sc1 = *(const float4*)(scale + ch + 4);
      const float4 sc2 = *(const float4*)(scale + ch + 8), sc3 = *(const float4*)(scale + ch + 12);
      const float4 sh0 = *(const float4*)(shift + ch),  sh1 = *(const float4*)(shift + ch + 4);
      const float4 sh2 = *(const float4*)(shift + ch + 8), sh3 = *(const float4*)(shift + ch + 12);
      const float4 bs0 = *(const float4*)(bias + ch),   bs1 = *(const float4*)(bias + ch + 4);
      const float4 bs2 = *(const float4*)(bias + ch + 8),  bs3 = *(const float4*)(bias + ch + 12);
#define BN4(v, s, h, b) { \
      v.x = fmaxf(fmaf(v.x + b.x, s.x, h.x), 0.f); v.y = fmaxf(fmaf(v.y + b.y, s.y, h.y), 0.f); \
      v.z = fmaxf(fmaf(v.z + b.z, s.z, h.z), 0.f); v.w = fmaxf(fmaf(v.w + b.w, s.w, h.w), 0.f); }
      BN4(pa0, sc0, sh0, bs0) BN4(pa1, sc1, sh1, bs1)
      BN4(pa2, sc2, sh2, bs2) BN4(pa3, sc3, sh3, bs3)
#undef BN4
    }
    // fp32 -> f16 hi/lo split (VALU, overlaps barrier wait)
    half8 h0, h1, l0, l1;
#define SPLIT4(v, H, L, b) { \
    H[b+0] = (_Float16)v.x; L[b+0] = (_Float16)(v.x - (float)H[b+0]); \
    H[b+1] = (_Float16)v.y; L[b+1] = (_Float16)(v.y - (float)H[b+1]); \
    H[b+2] = (_Float16)v.z; L[b+2] = (_Float16)(v.z - (float)H[b+2]); \
    H[b+3] = (_Float16)v.w; L[b+3] = (_Float16)(v.w - (float)H[b+3]); }
    SPLIT4(pa0, h0, l0, 0) SPLIT4(pa1, h0, l0, 4)
    SPLIT4(pa2, h1, l1, 0) SPLIT4(pa3, h1, l1, 4)
#undef SPLIT4
    __syncthreads();   // previous slab's frag reads done before overwrite
    *(half8*)&Ahs[sr][sk] = h0;  *(half8*)&Ahs[sr][sk + 8] = h1;
    *(half8*)&Als[sr][sk] = l0;  *(half8*)&Als[sr][sk + 8] = l1;
    *(uint4*)&Bhs[sr][sk] = pbh0; *(uint4*)&Bhs[sr][sk + 8] = pbh1;
    *(uint4*)&Bls[sr][sk] = pbl0; *(uint4*)&Bls[sr][sk + 8] = pbl1;
    __syncthreads();
    if (k0 + 32 < K) LOADSLAB(k0 + 32);  // prefetch overlaps MFMA below

    half8 fah[4], fal[4];
#pragma unroll
    for (int mf = 0; mf < 4; ++mf) {
      const int r = wm * 64 + mf * 16 + l15;
      fah[mf] = *(const half8*)&Ahs[r][g * 8];
      fal[mf] = *(const half8*)&Als[r][g * 8];
    }
#pragma unroll
    for (int nf = 0; nf < 4; ++nf) {
      const int c = wn * 64 + nf * 16 + l15;
      half8 fbh = *(const half8*)&Bhs[c][g * 8];
      half8 fbl = *(const half8*)&Bls[c][g * 8];
#pragma unroll
      for (int mf = 0; mf < 4; ++mf) {
        acc[mf][nf] = __builtin_amdgcn_mfma_f32_16x16x32_f16(fah[mf], fbh, acc[mf][nf], 0, 0, 0);
        acc[mf][nf] = __builtin_amdgcn_mfma_f32_16x16x32_f16(fah[mf], fbl, acc[mf][nf], 0, 0, 0);
        acc[mf][nf] = __builtin_amdgcn_mfma_f32_16x16x32_f16(fal[mf], fbh, acc[mf][nf], 0, 0, 0);
      }
    }
  }
#undef LOADSLAB
#pragma unroll
  for (int mf = 0; mf < 4; ++mf) {
#pragma unroll
    for (int nf = 0; nf < 4; ++nf) {
      const int r = row0 + wm * 64 + mf * 16 + g * 4;
      float* cp = Cm + (size_t)r * HID + col0 + wn * 64 + nf * 16 + l15;
#pragma unroll
      for (int reg = 0; reg < 4; ++reg) cp[(size_t)reg * HID] = acc[mf][nf][reg];
    }
  }
}

__global__ __launch_bounds__(256) void k_bn_stats(const float* __restrict__ A, const float* __restrict__ bias,
                                                  float* __restrict__ sums, float* __restrict__ sumsq) {
  const int c = threadIdx.x;
  const float b = bias[c];
  float s = 0.f, q = 0.f;
  const int r0 = blockIdx.x * (SMP / 256);
  for (int r = r0; r < r0 + (SMP / 256); ++r) {
    float h = A[(size_t)r * HID + c] + b;
    s += h;
    q = fmaf(h, h, q);
  }
  unsafeAtomicAdd(&sums[c], s);
  unsafeAtomicAdd(&sumsq[c], q);
}

// s3[i] = dot(relu(bn(A2[i,:]+b2)), W3[:,0]); one wave per row.
// BN+ReLU fused at load — bit-identical to the removed k_bn_apply pass.
__global__ __launch_bounds__(256) void k_gemv3(const float* __restrict__ A2, const float* __restrict__ W3,
                                               float* __restrict__ s3,
                                               const float* __restrict__ scale, const float* __restrict__ shift,
                                               const float* __restrict__ bias) {
  const int wave = threadIdx.x >> 6, lane = threadIdx.x & 63;
  const int row = blockIdx.x * 4 + wave;
  const int c = lane * 4;
  float4 v = *(const float4*)(A2 + (size_t)row * HID + c);
  const float4 sc = *(const float4*)(scale + c);
  const float4 sh = *(const float4*)(shift + c);
  const float4 bs = *(const float4*)(bias + c);
  v.x = fmaxf(fmaf(v.x + bs.x, sc.x, sh.x), 0.f);
  v.y = fmaxf(fmaf(v.y + bs.y, sc.y, sh.y), 0.f);
  v.z = fmaxf(fmaf(v.z + bs.z, sc.z, sh.z), 0.f);
  v.w = fmaxf(fmaf(v.w + bs.w, sc.w, sh.w), 0.f);
  float4 w = *(const float4*)(W3 + c);
  float d = v.x * w.x + v.y * w.y + v.z * w.z + v.w * w.w;
#pragma unroll
  for (int o = 32; o > 0; o >>= 1) d += __shfl_down(d, o);
  if (lane == 0) s3[row] = d;
}

extern "C" void kernel_launch(void* const* d_in, const int* in_sizes, int n_in,
                              void* d_out, int out_size, void* d_ws, size_t ws_size,
                              hipStream_t stream) {
  (void)in_sizes; (void)n_in; (void)out_size; (void)ws_size;
  const float* x   = (const float*)d_in[0];
  const int*  eidx = (const int*)d_in[1];
  const float* W1  = (const float*)d_in[2];
  const float* b1  = (const float*)d_in[3];
  const float* W2  = (const float*)d_in[4];
  const float* b2  = (const float*)d_in[5];
  const float* W3  = (const float*)d_in[6];
  const float* b3  = (const float*)d_in[7];
  const float* g1  = (const float*)d_in[8];
  const float* be1 = (const float*)d_in[9];
  const float* g2  = (const float*)d_in[10];
  const float* be2 = (const float*)d_in[11];
  const int* erow = eidx;
  const int* ecol = eidx + NEDGES;

  float* out = (float*)d_out;        // [32768] conv3 output
  float* outSamp = out + SMP;        // [32768] sampled indices as f32

  size_t off = 0;
  auto take = [&](size_t bytes) -> char* {
    char* p = (char*)d_ws + off;
    off += (bytes + 255) & ~(size_t)255;
    return p;
  };
  float* S       = (float*)take((size_t)SMP * HID * 4);  // support / s3
  float* A       = (float*)take((size_t)SMP * HID * 4);  // segsum output
  float* H       = (float*)take((size_t)SMP * HID * 4);  // (unused; kept for ws layout stability)
  float* E       = (float*)take(199994 * 4);             // down-sweep levels
  float* CS      = (float*)take(199994 * 4);             // up-sweep levels (CS[0..100000) = result)
  int*   deg     = (int*)take(NNODES * 4);
  int*   part    = (int*)take((size_t)NEDGES * 4);       // bucket-partitioned edge rows
  int*   lbaseg  = (int*)take((size_t)PA_BLOCKS * NBUCK * 4);  // per-block bucket bases
  int*   mapping = (int*)take(NNODES * 4);
  int*   sampled = (int*)take(SMP * 4);
  float* sums    = (float*)take(HID * 4 * 2);
  float* sumsq   = sums + HID;
  float* scale   = (float*)take(HID * 4);
  float* shift   = (float*)take(HID * 4);
  int*   cnt     = (int*)take(SMP * 4);
  int*   rowptr  = (int*)take((SMP + 1) * 4);
  int*   cursor  = (int*)take(SMP * 4);
  int*   srcidx  = (int*)take((size_t)NEDGES * 4);
  _Float16* W1h  = (_Float16*)take((size_t)INFEAT * HID * 2);  // [256][512]
  _Float16* W1l  = (_Float16*)take((size_t)INFEAT * HID * 2);
  _Float16* W2h  = (_Float16*)take((size_t)HID * HID * 2);     // [256][256]
  _Float16* W2l  = (_Float16*)take((size_t)HID * HID * 2);
  (void)H;
  // total ws need ~= 131 MB

  // one-time weight splits (f16 hi/lo, transposed); single launch
  k_wsplit<<<INFEAT + HID, 256, 0, stream>>>(W1, W1h, W1l, W2, W2h, W2l);

  // degree histogram, atomic-free (two-phase partition); k_part also clears mapping
  k_part<<<PA_BLOCKS, 256, 0, stream>>>(erow, part, lbaseg, mapping);
  k_count<<<NBUCK, 256, 0, stream>>>(part, lbaseg, deg);

  // cumsum: parallel bit-exact tree (down-sweep, mid, fused up-sweep)
  k_down<<<25, 256, 0, stream>>>(deg, E);
  k_mid<<<1, 1024, 0, stream>>>(E, CS);
  k_upall<<<25, 256, 0, stream>>>(CS + 193750, E, CS);

  k_sample<<<SMP / 256, 256, 0, stream>>>(CS, sampled, mapping, outSamp, cnt);

  // CSR over valid edges, keyed by destination position
  k_edge_count<<<(NEDGES + 255) / 256, 256, 0, stream>>>(erow, ecol, mapping, cnt);
  k_scan<<<1, 1024, 0, stream>>>(cnt, rowptr, cursor);
  k_edge_fill<<<(NEDGES + 255) / 256, 256, 0, stream>>>(erow, ecol, mapping, cursor, srcidx);

  // layer 1: conv(x@W1) -> BN stats (BN+relu applied lazily at layer-2 staging)
  k_gemm_h<<<dim3(SMP / 128, HID / 128), 256, 0, stream>>>(x, W1h, W1l, S, sampled, INFEAT,
                                                           nullptr, nullptr, nullptr);
  k_segsum<<<SMP / 4, 256, 0, stream>>>(S, rowptr, srcidx, A, sums);
  k_bn_stats<<<256, 256, 0, stream>>>(A, b1, sums, sumsq);
  k_bn_final<<<1, HID, 0, stream>>>(sums, sumsq, g1, be1, scale, shift);

  // layer 2: BN1+relu fused into A staging
  k_gemm_h<<<dim3(SMP / 128, HID / 128), 256, 0, stream>>>(A, W2h, W2l, S, nullptr, HID,
                                                           scale, shift, b1);
  k_segsum<<<SMP / 4, 256, 0, stream>>>(S, rowptr, srcidx, A, sums);
  k_bn_stats<<<256, 256, 0, stream>>>(A, b2, sums, sumsq);
  k_bn_final<<<1, HID, 0, stream>>>(sums, sumsq, g2, be2, scale, shift);

  // layer 3: gemv (BN2+relu fused at load) + CSR segsum + bias
  k_gemv3<<<SMP / 4, 256, 0, stream>>>(A, W3, S, scale, shift, b2);  // S reused as s3
  k_segsum_sc<<<SMP / 256, 256, 0, stream>>>(S, rowptr, srcidx, b3, out);
}